// Round 7
// baseline (820.650 us; speedup 1.0000x reference)
//
#include <hip/hip_runtime.h>
#include <hip/hip_bf16.h>
#include <math.h>

#define T_TOK 3072
#define HID_D 5120
#define NH 16
#define DN 128
#define DR 64
#define DQK 192
#define DV 128
#define QRANK 1536
#define KVRANK 512
#define MERGED_N 2176   // 1536 (q_a) + 640 (kv_a padded from 576)

typedef __attribute__((ext_vector_type(8))) short short8;
typedef __attribute__((ext_vector_type(4))) float f32x4;
typedef unsigned short u16;

__device__ __forceinline__ u16 f2bf(float f) {
    unsigned int u = __float_as_uint(f);
    unsigned int lsb = (u >> 16) & 1;
    u += 0x7fffu + lsb;
    return (u16)(u >> 16);
}
__device__ __forceinline__ float bf2f(u16 v) {
    return __uint_as_float(((unsigned int)v) << 16);
}

__device__ __forceinline__ void gload_lds16(const u16* g, u16* l) {
    __builtin_amdgcn_global_load_lds((const __attribute__((address_space(1))) void*)g,
                                     (__attribute__((address_space(3))) void*)l, 16, 0, 0);
}

// ---------------- fp32 -> bf16 elementwise ----------------
__global__ __launch_bounds__(256) void convert_bf_k(const float* __restrict__ x,
                                                    u16* __restrict__ y, int n4)
{
    const int i = blockIdx.x * 256 + threadIdx.x;
    if (i < n4) {
        float4 v = ((const float4*)x)[i];
        ushort4 o;
        o.x = f2bf(v.x); o.y = f2bf(v.y); o.z = f2bf(v.z); o.w = f2bf(v.w);
        ((ushort4*)y)[i] = o;
    }
}

// ---------------- fp32 K x N  ->  bf16 N x K (transposed, zero-pad cols >= N) ----------------
__global__ __launch_bounds__(256) void transpose_conv_k(const float* __restrict__ W,
                                                        u16* __restrict__ WT,
                                                        int K, int N)
{
    __shared__ float tile[32][33];
    const int n0 = blockIdx.x * 32, k0 = blockIdx.y * 32;
    const int tx = threadIdx.x & 31, ty = threadIdx.x >> 5;
#pragma unroll
    for (int i = 0; i < 32; i += 8) {
        const int nn = n0 + tx;
        tile[ty + i][tx] = (nn < N) ? W[(size_t)(k0 + ty + i) * N + nn] : 0.f;
    }
    __syncthreads();
#pragma unroll
    for (int i = 0; i < 32; i += 8) {
        WT[(size_t)(n0 + ty + i) * K + k0 + tx] = f2bf(tile[tx][ty + i]);
    }
}

// ---------------- bf16 MFMA GEMM helpers ----------------
__device__ __forceinline__ void gemm_stage(const u16* a0, const u16* a1,
                                           const u16* b0, const u16* b1,
                                           u16* As, u16* Bs, int tid)
{
    gload_lds16(a0, As + tid * 8);
    gload_lds16(a1, As + tid * 8 + 64 * 32);
    gload_lds16(b0, Bs + tid * 8);
    gload_lds16(b1, Bs + tid * 8 + 64 * 32);
}

__device__ __forceinline__ void gemm_compute(const u16* As, const u16* Bs,
                                             int wr, int wc, int l16, int quad,
                                             f32x4 acc[4][4])
{
    short8 af[4], bf[4];
#pragma unroll
    for (int mi = 0; mi < 4; ++mi)
        af[mi] = *(const short8*)(As + (wr + mi * 16 + l16) * 32 + quad * 8);
#pragma unroll
    for (int ni = 0; ni < 4; ++ni)
        bf[ni] = *(const short8*)(Bs + (wc + ni * 16 + l16) * 32 + quad * 8);
#pragma unroll
    for (int mi = 0; mi < 4; ++mi)
#pragma unroll
        for (int ni = 0; ni < 4; ++ni)
            acc[mi][ni] = __builtin_amdgcn_mfma_f32_16x16x32_bf16(
                af[mi], bf[ni], acc[mi][ni], 0, 0, 0);
}

// ---------------- bf16 MFMA GEMM, B transposed: C = A @ BT^T ----------------
// 2-phase double-buffer (T3 minimal): STAGE next tile -> compute current ->
// vmcnt(0)+barrier AFTER compute. Static even/odd buffers so no false aliasing.
// XCD-swizzled block mapping.
template <bool BF16_OUT>
__global__ __launch_bounds__(256) void bgemm_bt_k(
    const u16* __restrict__ A, const u16* __restrict__ BT, void* __restrict__ C,
    int Nreal, int K, int lda, int ldb, int ldc)
{
    __shared__ __attribute__((aligned(16))) u16 As0[128 * 32];
    __shared__ __attribute__((aligned(16))) u16 Bs0[128 * 32];
    __shared__ __attribute__((aligned(16))) u16 As1[128 * 32];
    __shared__ __attribute__((aligned(16))) u16 Bs1[128 * 32];

    const int tid  = threadIdx.x;
    const int wave = tid >> 6, lane = tid & 63;
    const int quad = lane >> 4, l16 = lane & 15;
    const int wr = (wave >> 1) * 64, wc = (wave & 1) * 64;

    const int gx  = (int)gridDim.x;
    const int nwg = gx * (int)gridDim.y;
    const int lin = (int)blockIdx.y * gx + (int)blockIdx.x;
    const int wid = (lin & 7) * (nwg >> 3) + (lin >> 3);
    const int row0 = (wid / gx) * 128, col0 = (wid % gx) * 128;

    f32x4 acc[4][4];
#pragma unroll
    for (int i = 0; i < 4; ++i)
#pragma unroll
        for (int j = 0; j < 4; ++j) acc[i][j] = (f32x4){0.f, 0.f, 0.f, 0.f};

    const int sr  = tid >> 2;
    const int skc = (tid & 3) * 8;
    const u16* ap0 = A  + (size_t)(row0 + sr)      * lda + skc;
    const u16* ap1 = A  + (size_t)(row0 + sr + 64) * lda + skc;
    const u16* bp0 = BT + (size_t)(col0 + sr)      * ldb + skc;
    const u16* bp1 = BT + (size_t)(col0 + sr + 64) * ldb + skc;

    const int nk = K >> 5;
    // prologue: tile 0 -> buf0
    gemm_stage(ap0, ap1, bp0, bp1, As0, Bs0, tid);
    asm volatile("s_waitcnt vmcnt(0)" ::: "memory");
    __builtin_amdgcn_s_barrier();
    __builtin_amdgcn_sched_barrier(0);

    for (int kt = 0; kt < nk; ++kt) {
        const int nxt = (kt + 1) << 5;
        if ((kt & 1) == 0) {
            if (kt + 1 < nk)
                gemm_stage(ap0 + nxt, ap1 + nxt, bp0 + nxt, bp1 + nxt, As1, Bs1, tid);
            gemm_compute(As0, Bs0, wr, wc, l16, quad, acc);
        } else {
            if (kt + 1 < nk)
                gemm_stage(ap0 + nxt, ap1 + nxt, bp0 + nxt, bp1 + nxt, As0, Bs0, tid);
            gemm_compute(As1, Bs1, wr, wc, l16, quad, acc);
        }
        // loads for the next tile had this tile's compute to land
        asm volatile("s_waitcnt vmcnt(0)" ::: "memory");
        __builtin_amdgcn_s_barrier();
        __builtin_amdgcn_sched_barrier(0);
    }

#pragma unroll
    for (int mi = 0; mi < 4; ++mi) {
#pragma unroll
        for (int ni = 0; ni < 4; ++ni) {
            const int col_g = col0 + wc + ni * 16 + l16;
            if (col_g < Nreal) {
#pragma unroll
                for (int r = 0; r < 4; ++r) {
                    const int row_g = row0 + wr + mi * 16 + quad * 4 + r;
                    if (BF16_OUT)
                        ((u16*)C)[(size_t)row_g * ldc + col_g] = f2bf(acc[mi][ni][r]);
                    else
                        ((float*)C)[(size_t)row_g * ldc + col_g] = acc[mi][ni][r];
                }
            }
        }
    }
}

// ---------------- RMSNorm: bf16 strided in -> bf16 compact out (vectorized) ----------------
__global__ __launch_bounds__(256) void rmsnorm_bf_k(const u16* __restrict__ x,
                                                    const float* __restrict__ w,
                                                    u16* __restrict__ y,
                                                    int width, int stride, int off)
{
    const int row = blockIdx.x;
    const u16* xr = x + (size_t)row * stride + off;
    const int nch = width >> 3;
    float ss = 0.f;
    for (int i = threadIdx.x; i < nch; i += 256) {
        short8 v = *(const short8*)(xr + i * 8);
#pragma unroll
        for (int j = 0; j < 8; ++j) { const float f = bf2f((u16)v[j]); ss += f * f; }
    }
    __shared__ float red[256];
    red[threadIdx.x] = ss;
    __syncthreads();
    for (int s2 = 128; s2 > 0; s2 >>= 1) {
        if (threadIdx.x < s2) red[threadIdx.x] += red[threadIdx.x + s2];
        __syncthreads();
    }
    const float scale = rsqrtf(red[0] / (float)width + 1e-6f);
    u16* yr = y + (size_t)row * width;
    for (int i = threadIdx.x; i < nch; i += 256) {
        short8 v = *(const short8*)(xr + i * 8);
        const float4 w0 = *(const float4*)(w + i * 8);
        const float4 w1 = *(const float4*)(w + i * 8 + 4);
        short8 o;
        o[0] = (short)f2bf(bf2f((u16)v[0]) * scale * w0.x);
        o[1] = (short)f2bf(bf2f((u16)v[1]) * scale * w0.y);
        o[2] = (short)f2bf(bf2f((u16)v[2]) * scale * w0.z);
        o[3] = (short)f2bf(bf2f((u16)v[3]) * scale * w0.w);
        o[4] = (short)f2bf(bf2f((u16)v[4]) * scale * w1.x);
        o[5] = (short)f2bf(bf2f((u16)v[5]) * scale * w1.y);
        o[6] = (short)f2bf(bf2f((u16)v[6]) * scale * w1.z);
        o[7] = (short)f2bf(bf2f((u16)v[7]) * scale * w1.w);
        *(short8*)(yr + i * 8) = o;
    }
}

// ---------------- RoPE on q (bf16 in) + llama_4 scaling -> bf16 out (vectorized) ----------------
__global__ __launch_bounds__(256) void rope_scale_q_bf_k(const u16* __restrict__ q, const int* __restrict__ positions,
                                  const float* __restrict__ scaling,
                                  const float* __restrict__ cs_cache, u16* __restrict__ qb)
{
    const int t = blockIdx.x;
    const int pos = positions[t];
    const float* cs = cs_cache + (size_t)pos * DR;
    const float s = scaling[t];
    __shared__ float c_sh[32], s_sh[32];
    if (threadIdx.x < 32) {
        c_sh[threadIdx.x] = cs[threadIdx.x];
        s_sh[threadIdx.x] = cs[32 + threadIdx.x];
    }
    __syncthreads();
    const u16* qt = q + (size_t)t * NH * DQK;
    u16* qo = qb + (size_t)t * NH * DQK;
    for (int cc = threadIdx.x; cc < NH * 20; cc += 256) {
        const int hh = cc / 20, c = cc % 20;
        const u16* qr = qt + hh * DQK;
        u16* qw = qo + hh * DQK;
        if (c < 16) {
            short8 v = *(const short8*)(qr + c * 8);
            short8 o;
#pragma unroll
            for (int j = 0; j < 8; ++j) o[j] = (short)f2bf(bf2f((u16)v[j]) * s);
            *(short8*)(qw + c * 8) = o;
        } else {
            const int d0 = (c - 16) * 8;
            short8 x1 = *(const short8*)(qr + 128 + d0);
            short8 x2 = *(const short8*)(qr + 160 + d0);
            short8 o1, o2;
#pragma unroll
            for (int j = 0; j < 8; ++j) {
                const float a = bf2f((u16)x1[j]), b = bf2f((u16)x2[j]);
                const float cv = c_sh[d0 + j], sv = s_sh[d0 + j];
                o1[j] = (short)f2bf((a * cv - b * sv) * s);
                o2[j] = (short)f2bf((b * cv + a * sv) * s);
            }
            *(short8*)(qw + 128 + d0) = o1;
            *(short8*)(qw + 160 + d0) = o2;
        }
    }
}

// ---------------- RoPE on k_pe (pre-norm merged-latent tail, bf16) -> bf16 ----------------
__global__ void rope_k_bf_k(const u16* __restrict__ qa_lat, u16* __restrict__ kpe,
                            const int* __restrict__ positions,
                            const float* __restrict__ cs_cache)
{
    const int t = blockIdx.x;
    const int d = threadIdx.x;
    if (d >= 32) return;
    const int pos = positions[t];
    const float* cs = cs_cache + (size_t)pos * DR;
    const float c = cs[d], sn = cs[32 + d];
    const u16* lr = qa_lat + (size_t)t * MERGED_N + QRANK + KVRANK;
    const float x1 = bf2f(lr[d]), x2 = bf2f(lr[32 + d]);
    kpe[(size_t)t * DR + d]      = f2bf(x1 * c - x2 * sn);
    kpe[(size_t)t * DR + 32 + d] = f2bf(x2 * c + x1 * sn);
}

// ---------------- transpose V: kv_bf (T,NH,256)[...,128:] -> vt (NH,DV,T) ----------------
__global__ __launch_bounds__(256) void transpose_v_k(const u16* __restrict__ kvb,
                                                     u16* __restrict__ vt)
{
    __shared__ u16 tile[64][72];
    const int t0 = blockIdx.x * 64, d0 = blockIdx.y * 64, h = blockIdx.z;
    const int tid = threadIdx.x;
    for (int cc = tid; cc < 64 * 8; cc += 256) {
        const int row = cc >> 3, c = (cc & 7) * 8;   // row=t, c=dv
        *(short8*)&tile[row][c] =
            *(const short8*)(kvb + ((size_t)(t0 + row) * NH + h) * (DN + DV) + DN + d0 + c);
    }
    __syncthreads();
    for (int cc = tid; cc < 64 * 8; cc += 256) {
        const int drow = cc >> 3, c = (cc & 7) * 8;  // drow=dv, c=t
        short8 s;
#pragma unroll
        for (int j = 0; j < 8; ++j) s[j] = tile[c + j][drow];
        *(short8*)(vt + ((size_t)h * DV + d0 + drow) * T_TOK + t0 + c) = s;
    }
}

// ---------------- bf16 MFMA flash attention v7 (R5 structure, proven 233 us) ----------------
// 512 thr, 8 waves, BM=128, BN=64, K+kpe staged in padded LDS double-buffer.
// RAW s_barrier + asm waits placed AFTER compute; per tile: ds_write t+1 (regs) |
// issue loads t+2 | compute t | vmcnt(0)+lgkmcnt(0) | s_barrier | sched_barrier.
// XCD-chunked mapping; V direct from L2; setprio around MFMA clusters.
#define ATT_BM 128
#define ATT_BN 64
#define KS_STRIDE 200            // u16 per row: 192 data + 8 pad
#define KS_BUF (64 * KS_STRIDE)  // u16 per buffer
__global__ __launch_bounds__(512) void attn_mfma_k(
    const u16* __restrict__ qb, const u16* __restrict__ kvb,
    const u16* __restrict__ kpeb, const u16* __restrict__ vt,
    u16* __restrict__ attnb)
{
    __shared__ u16 Ks[2 * KS_BUF];    // 51.2 KB double-buffered K tile (incl. kpe)
    __shared__ u16 Ps[8][16][72];     // per-wave P bounce, +8 pad

    const int tid  = threadIdx.x;
    const int wave = tid >> 6;
    const int lane = tid & 63;
    const int quad = lane >> 4;
    const int l16  = lane & 15;

    // XCD-chunked mapping: bid%8 -> XCD, 48 blocks/chunk = 2 heads x 24 q-blocks.
    const int bid   = (int)blockIdx.x;
    const int chunk = bid & 7;
    const int local = bid >> 3;                 // 0..47
    const int h     = chunk * 2 + (local & 1);
    const int qblk  = 23 - (local >> 1);        // heavy blocks first
    const int q0    = qblk * ATT_BM;
    const int wrow0 = q0 + wave * 16;
    const int qrow  = wrow0 + l16;

    short8 qf[6];
    {
        const u16* qp = qb + ((size_t)qrow * NH + h) * DQK + quad * 8;
#pragma unroll
        for (int c = 0; c < 6; ++c)
            qf[c] = *(const short8*)(qp + c * 32);
    }

    // staging descriptors: 64 rows x 24 chunks of 16B = 1536 -> 3 per thread
    const u16* gp0; const u16* gp1; const u16* gp2;
    size_t gs0, gs1, gs2;
    int lo0, lo1, lo2;
    {
        const int cc0 = tid,       r0 = cc0 / 24, c0 = cc0 % 24;
        const int cc1 = tid + 512, r1 = cc1 / 24, c1 = cc1 % 24;
        const int cc2 = tid + 1024, r2 = cc2 / 24, c2 = cc2 % 24;
        gp0 = (c0 < 16) ? kvb + ((size_t)r0 * NH + h) * (DN + DV) + c0 * 8
                        : kpeb + (size_t)r0 * DR + (c0 - 16) * 8;
        gs0 = (c0 < 16) ? (size_t)ATT_BN * NH * (DN + DV) : (size_t)ATT_BN * DR;
        lo0 = r0 * KS_STRIDE + c0 * 8;
        gp1 = (c1 < 16) ? kvb + ((size_t)r1 * NH + h) * (DN + DV) + c1 * 8
                        : kpeb + (size_t)r1 * DR + (c1 - 16) * 8;
        gs1 = (c1 < 16) ? (size_t)ATT_BN * NH * (DN + DV) : (size_t)ATT_BN * DR;
        lo1 = r1 * KS_STRIDE + c1 * 8;
        gp2 = (c2 < 16) ? kvb + ((size_t)r2 * NH + h) * (DN + DV) + c2 * 8
                        : kpeb + (size_t)r2 * DR + (c2 - 16) * 8;
        gs2 = (c2 < 16) ? (size_t)ATT_BN * NH * (DN + DV) : (size_t)ATT_BN * DR;
        lo2 = r2 * KS_STRIDE + c2 * 8;
    }

    f32x4 oacc[8];
#pragma unroll
    for (int t = 0; t < 8; ++t) oacc[t] = (f32x4){0.f, 0.f, 0.f, 0.f};
    float m_old[4], l_run[4];
#pragma unroll
    for (int r = 0; r < 4; ++r) { m_old[r] = -1e30f; l_run[r] = 0.f; }

    const u16* vbase = vt + ((size_t)h * DV + l16) * T_TOK + quad * 8;
    const int nkt = 2 * (qblk + 1);             // 64-key tiles incl. diagonal

    // prologue: tile 0 -> regs -> buf0; tile 1 loads in flight
    short8 s0 = *(const short8*)gp0;
    short8 s1 = *(const short8*)gp1;
    short8 s2 = *(const short8*)gp2;
    asm volatile("s_waitcnt vmcnt(0)" ::: "memory");
    *(short8*)(Ks + lo0) = s0;
    *(short8*)(Ks + lo1) = s1;
    *(short8*)(Ks + lo2) = s2;
    s0 = *(const short8*)(gp0 + gs0);
    s1 = *(const short8*)(gp1 + gs1);
    s2 = *(const short8*)(gp2 + gs2);
    asm volatile("s_waitcnt vmcnt(0) lgkmcnt(0)" ::: "memory");
    __builtin_amdgcn_s_barrier();
    __builtin_amdgcn_sched_barrier(0);

    int cur = 0;
    for (int kt = 0; kt < nkt; ++kt) {
        // stage tile kt+1 from regs into the other buffer (overlaps compute below)
        if (kt + 1 < nkt) {
            u16* wp = Ks + (cur ^ 1) * KS_BUF;
            *(short8*)(wp + lo0) = s0;
            *(short8*)(wp + lo1) = s1;
            *(short8*)(wp + lo2) = s2;
        }
        // issue tile kt+2 loads -> regs (complete by this iter's end-wait)
        if (kt + 2 < nkt) {
            const size_t o = (size_t)(kt + 2);
            s0 = *(const short8*)(gp0 + o * gs0);
            s1 = *(const short8*)(gp1 + o * gs1);
            s2 = *(const short8*)(gp2 + o * gs2);
        }

        const int k0 = kt * ATT_BN;
        if (k0 <= wrow0 + 15) {                 // wave has >=1 unmasked row
            const u16* kb = Ks + cur * KS_BUF;
            f32x4 sacc[4];
#pragma unroll
            for (int t = 0; t < 4; ++t) sacc[t] = (f32x4){0.f, 0.f, 0.f, 0.f};
            __builtin_amdgcn_s_setprio(1);
#pragma unroll
            for (int t = 0; t < 4; ++t) {
                const u16* kp = kb + (t * 16 + l16) * KS_STRIDE + quad * 8;
#pragma unroll
                for (int c = 0; c < 6; ++c) {
                    short8 bfrag = *(const short8*)(kp + c * 32);
                    sacc[t] = __builtin_amdgcn_mfma_f32_16x16x32_bf16(qf[c], bfrag, sacc[t], 0, 0, 0);
                }
            }
            __builtin_amdgcn_s_setprio(0);
            // prefetch V ch0 under softmax (independent of P)
            short8 vv[8];
#pragma unroll
            for (int t = 0; t < 8; ++t)
                vv[t] = *(const short8*)(vbase + (size_t)t * 16 * T_TOK + k0);

            const float sc = 0.07216878364870322f;   // 1/sqrt(192)
            const int rbase = wrow0 + quad * 4;
            if (k0 + ATT_BN - 1 > wrow0) {
                // diagonal-ish: causal mask
#pragma unroll
                for (int t = 0; t < 4; ++t) {
                    const int colg = k0 + t * 16 + l16;
#pragma unroll
                    for (int r = 0; r < 4; ++r) {
                        const float s = sacc[t][r] * sc;
                        sacc[t][r] = (rbase + r >= colg) ? s : -1e30f;
                    }
                }
            } else {
#pragma unroll
                for (int t = 0; t < 4; ++t)
#pragma unroll
                    for (int r = 0; r < 4; ++r) sacc[t][r] *= sc;
            }
            float alpha[4];
#pragma unroll
            for (int r = 0; r < 4; ++r) {
                float mx = fmaxf(fmaxf(sacc[0][r], sacc[1][r]), fmaxf(sacc[2][r], sacc[3][r]));
                mx = fmaxf(mx, __shfl_xor(mx, 1));
                mx = fmaxf(mx, __shfl_xor(mx, 2));
                mx = fmaxf(mx, __shfl_xor(mx, 4));
                mx = fmaxf(mx, __shfl_xor(mx, 8));
                const float mnew = fmaxf(m_old[r], mx);
                alpha[r] = __expf(m_old[r] - mnew);
                float sum = 0.f;
#pragma unroll
                for (int t = 0; t < 4; ++t) {
                    const float p = __expf(sacc[t][r] - mnew);
                    sacc[t][r] = p;
                    sum += p;
                }
                sum += __shfl_xor(sum, 1);
                sum += __shfl_xor(sum, 2);
                sum += __shfl_xor(sum, 4);
                sum += __shfl_xor(sum, 8);
                l_run[r] = l_run[r] * alpha[r] + sum;
                m_old[r] = mnew;
            }
            // P (C-layout) -> per-wave LDS as bf16 (A-layout source for PV)
#pragma unroll
            for (int t = 0; t < 4; ++t)
#pragma unroll
                for (int r = 0; r < 4; ++r)
                    Ps[wave][quad * 4 + r][t * 16 + l16] = f2bf(sacc[t][r]);
            // issue V ch1 now: lands under Ps readback + PV ch0 MFMAs
            short8 ww[8];
#pragma unroll
            for (int t = 0; t < 8; ++t)
                ww[t] = *(const short8*)(vbase + (size_t)t * 16 * T_TOK + k0 + 32);
#pragma unroll
            for (int t = 0; t < 8; ++t)
#pragma unroll
                for (int r = 0; r < 4; ++r)
                    oacc[t][r] *= alpha[r];
            // same-wave LDS write->read: compiler-inserted lgkmcnt, no barrier needed
            short8 pfrag0 = *(const short8*)&Ps[wave][l16][quad * 8];
            short8 pfrag1 = *(const short8*)&Ps[wave][l16][32 + quad * 8];
            __builtin_amdgcn_s_setprio(1);
#pragma unroll
            for (int t = 0; t < 8; ++t)
                oacc[t] = __builtin_amdgcn_mfma_f32_16x16x32_bf16(pfrag0, vv[t], oacc[t], 0, 0, 0);
#pragma unroll
            for (int t = 0; t < 8; ++t)
                oacc[t] = __builtin_amdgcn_mfma_f32_16x16x32_bf16(pfrag1, ww[t], oacc[t], 0, 0, 0);
            __builtin_amdgcn_s_setprio(0);
        }

        // end-of-tile sync: loads for kt+2 had the whole compute to land
        asm volatile("s_waitcnt vmcnt(0) lgkmcnt(0)" ::: "memory");
        __builtin_amdgcn_s_barrier();
        __builtin_amdgcn_sched_barrier(0);
        cur ^= 1;
    }

#pragma unroll
    for (int r = 0; r < 4; ++r) {
        const float linv = 1.f / l_run[r];
        const int row_g = wrow0 + quad * 4 + r;
        u16* op = attnb + (size_t)row_g * (NH * DV) + h * DV;
#pragma unroll
        for (int t = 0; t < 8; ++t)
            op[t * 16 + l16] = f2bf(oacc[t][r] * linv);
    }
}

extern "C" void kernel_launch(void* const* d_in, const int* in_sizes, int n_in,
                              void* d_out, int out_size, void* d_ws, size_t ws_size,
                              hipStream_t stream)
{
    const int*   positions = (const int*)d_in[0];
    const float* hidden    = (const float*)d_in[1];
    const float* scaling   = (const float*)d_in[2];
    const float* w_q_a     = (const float*)d_in[3];
    const float* q_a_ln_w  = (const float*)d_in[4];
    const float* w_q_b     = (const float*)d_in[5];
    const float* w_kv_a    = (const float*)d_in[6];
    const float* kv_a_ln_w = (const float*)d_in[7];
    const float* w_kv_b    = (const float*)d_in[8];
    const float* w_o       = (const float*)d_in[9];
    const float* cs_cache  = (const float*)d_in[10];
    float* out = (float*)d_out;

    char* p = (char*)d_ws;
    auto alloc = [&](size_t bytes) { char* r = p; p += (bytes + 255) & ~(size_t)255; return r; };

    // region H: hidden_bf (31.5MB), later reused as qraw_bf (18.9MB)
    char* regH      = alloc((size_t)T_TOK * HID_D * 2);
    u16*  hidden_bf = (u16*)regH;
    u16*  qraw_bf   = (u16*)regH;
    // region Q: qa_lat (13.4MB) + q_a_norm (9.4MB); later reused as qb (18.9MB)
    char* regQ      = alloc((size_t)T_TOK * MERGED_N * 2 + (size_t)T_TOK * QRANK * 2);
    u16*  qa_lat    = (u16*)regQ;
    u16*  q_a_norm  = (u16*)(regQ + (size_t)T_TOK * MERGED_N * 2);
    u16*  qb        = (u16*)regQ;
    u16* kv_a_norm = (u16*)alloc((size_t)T_TOK * KVRANK * 2);
    u16* kpe_bf    = (u16*)alloc((size_t)T_TOK * DR * 2);
    u16* kv_bf     = (u16*)alloc((size_t)T_TOK * NH * (DN + DV) * 2);
    u16* vt        = (u16*)alloc((size_t)NH * DV * T_TOK * 2);
    u16* attnb     = (u16*)alloc((size_t)T_TOK * NH * DV * 2);
    u16* wqakva_bt = (u16*)alloc((size_t)MERGED_N * HID_D * 2);
    u16* wqb_bt    = (u16*)alloc((size_t)(NH * DQK) * QRANK * 2);
    u16* wkvb_bt   = (u16*)alloc((size_t)(NH * (DN + DV)) * KVRANK * 2);
    u16* wo_bt     = (u16*)alloc((size_t)HID_D * (NH * DV) * 2);

    const dim3 blk(256);

    convert_bf_k<<<dim3((T_TOK * HID_D / 4 + 255) / 256), blk, 0, stream>>>(
        hidden, hidden_bf, T_TOK * HID_D / 4);
    // merged weight transpose: rows [0,1536) = w_q_a^T, rows [1536,2176) = w_kv_a^T (zero-padded)
    transpose_conv_k<<<dim3(QRANK / 32, HID_D / 32), blk, 0, stream>>>(
        w_q_a, wqakva_bt, HID_D, QRANK);
    transpose_conv_k<<<dim3(640 / 32, HID_D / 32), blk, 0, stream>>>(
        w_kv_a, wqakva_bt + (size_t)QRANK * HID_D, HID_D, KVRANK + DR);
    transpose_conv_k<<<dim3(NH * DQK / 32, QRANK / 32), blk, 0, stream>>>(w_q_b, wqb_bt, QRANK, NH * DQK);
    transpose_conv_k<<<dim3(NH * (DN + DV) / 32, KVRANK / 32), blk, 0, stream>>>(w_kv_b, wkvb_bt, KVRANK, NH * (DN + DV));
    transpose_conv_k<<<dim3(HID_D / 32, NH * DV / 32), blk, 0, stream>>>(w_o, wo_bt, NH * DV, HID_D);

    // merged G1+G2: qa_lat = hidden @ [w_q_a | w_kv_a]  (bf16 out, Nreal=2112)
    bgemm_bt_k<true><<<dim3(MERGED_N / 128, T_TOK / 128), blk, 0, stream>>>(
        hidden_bf, wqakva_bt, qa_lat, QRANK + KVRANK + DR, HID_D, HID_D, HID_D, MERGED_N);
    // k_pe rope from pre-norm latent tail (cols 2048..2111 of qa_lat)
    rope_k_bf_k<<<dim3(T_TOK), dim3(64), 0, stream>>>(qa_lat, kpe_bf, positions, cs_cache);
    // rmsnorms -> compact bf16
    rmsnorm_bf_k<<<dim3(T_TOK), blk, 0, stream>>>(qa_lat, q_a_ln_w, q_a_norm, QRANK, MERGED_N, 0);
    rmsnorm_bf_k<<<dim3(T_TOK), blk, 0, stream>>>(qa_lat, kv_a_ln_w, kv_a_norm, KVRANK, MERGED_N, QRANK);
    // G3: qraw = q_a_norm @ w_q_b  (bf16 out, into region H)
    bgemm_bt_k<true><<<dim3(NH * DQK / 128, T_TOK / 128), blk, 0, stream>>>(
        q_a_norm, wqb_bt, qraw_bf, NH * DQK, QRANK, QRANK, QRANK, NH * DQK);
    // rope + scaling on q -> qb (region Q; qa_lat/q_a_norm dead)
    rope_scale_q_bf_k<<<dim3(T_TOK), blk, 0, stream>>>(qraw_bf, positions, scaling, cs_cache, qb);
    // G4: kv = kv_a_norm @ w_kv_b  (bf16 out)
    bgemm_bt_k<true><<<dim3(NH * (DN + DV) / 128, T_TOK / 128), blk, 0, stream>>>(
        kv_a_norm, wkvb_bt, kv_bf, NH * (DN + DV), KVRANK, KVRANK, KVRANK, NH * (DN + DV));
    // global V transpose: vt[h][dv][t]
    transpose_v_k<<<dim3(T_TOK / 64, DV / 64, NH), blk, 0, stream>>>(kv_bf, vt);
    // flash attention v7 (R5 structure: counted-wait pipeline, raw barriers, XCD-chunked)
    attn_mfma_k<<<dim3(384), dim3(512), 0, stream>>>(qb, kv_bf, kpe_bf, vt, attnb);
    // G5: out = attn @ w_o  (fp32 out)
    bgemm_bt_k<false><<<dim3(HID_D / 128, T_TOK / 128), blk, 0, stream>>>(
        attnb, wo_bt, out, HID_D, NH * DV, NH * DV, NH * DV, HID_D);
}

// Round 8
// 759.640 us; speedup vs baseline: 1.0803x; 1.0803x over previous
//
#include <hip/hip_runtime.h>
#include <hip/hip_bf16.h>
#include <math.h>

#define T_TOK 3072
#define HID_D 5120
#define NH 16
#define DN 128
#define DR 64
#define DQK 192
#define DV 128
#define QRANK 1536
#define KVRANK 512
#define MERGED_N 2176   // 1536 (q_a) + 640 (kv_a padded from 576)

typedef __attribute__((ext_vector_type(8))) short short8;
typedef __attribute__((ext_vector_type(4))) float f32x4;
typedef unsigned short u16;

__device__ __forceinline__ u16 f2bf(float f) {
    unsigned int u = __float_as_uint(f);
    unsigned int lsb = (u >> 16) & 1;
    u += 0x7fffu + lsb;
    return (u16)(u >> 16);
}
__device__ __forceinline__ float bf2f(u16 v) {
    return __uint_as_float(((unsigned int)v) << 16);
}

__device__ __forceinline__ void gload_lds16(const u16* g, u16* l) {
    __builtin_amdgcn_global_load_lds((const __attribute__((address_space(1))) void*)g,
                                     (__attribute__((address_space(3))) void*)l, 16, 0, 0);
}

// ---------------- fp32 -> bf16 elementwise ----------------
__global__ __launch_bounds__(256) void convert_bf_k(const float* __restrict__ x,
                                                    u16* __restrict__ y, int n4)
{
    const int i = blockIdx.x * 256 + threadIdx.x;
    if (i < n4) {
        float4 v = ((const float4*)x)[i];
        ushort4 o;
        o.x = f2bf(v.x); o.y = f2bf(v.y); o.z = f2bf(v.z); o.w = f2bf(v.w);
        ((ushort4*)y)[i] = o;
    }
}

// ---------------- fp32 K x N  ->  bf16 N x K (transposed, zero-pad cols >= N) ----------------
__global__ __launch_bounds__(256) void transpose_conv_k(const float* __restrict__ W,
                                                        u16* __restrict__ WT,
                                                        int K, int N)
{
    __shared__ float tile[32][33];
    const int n0 = blockIdx.x * 32, k0 = blockIdx.y * 32;
    const int tx = threadIdx.x & 31, ty = threadIdx.x >> 5;
#pragma unroll
    for (int i = 0; i < 32; i += 8) {
        const int nn = n0 + tx;
        tile[ty + i][tx] = (nn < N) ? W[(size_t)(k0 + ty + i) * N + nn] : 0.f;
    }
    __syncthreads();
#pragma unroll
    for (int i = 0; i < 32; i += 8) {
        WT[(size_t)(n0 + ty + i) * K + k0 + tx] = f2bf(tile[tx][ty + i]);
    }
}

// ---------------- bf16 MFMA GEMM, B transposed: C = A @ BT^T, XCD-swizzled ----------------
// (R5 version: gload_lds staging + __syncthreads; the 2-phase graft regressed in R7.)
template <bool BF16_OUT>
__global__ __launch_bounds__(256) void bgemm_bt_k(
    const u16* __restrict__ A, const u16* __restrict__ BT, void* __restrict__ C,
    int Nreal, int K, int lda, int ldb, int ldc)
{
    __shared__ __attribute__((aligned(16))) u16 As[128 * 32];
    __shared__ __attribute__((aligned(16))) u16 Bs[128 * 32];

    const int tid  = threadIdx.x;
    const int wave = tid >> 6, lane = tid & 63;
    const int quad = lane >> 4, l16 = lane & 15;
    const int wr = (wave >> 1) * 64, wc = (wave & 1) * 64;

    const int gx  = (int)gridDim.x;
    const int nwg = gx * (int)gridDim.y;
    const int lin = (int)blockIdx.y * gx + (int)blockIdx.x;
    const int wid = (lin & 7) * (nwg >> 3) + (lin >> 3);
    const int row0 = (wid / gx) * 128, col0 = (wid % gx) * 128;

    f32x4 acc[4][4];
#pragma unroll
    for (int i = 0; i < 4; ++i)
#pragma unroll
        for (int j = 0; j < 4; ++j) acc[i][j] = (f32x4){0.f, 0.f, 0.f, 0.f};

    const int sr  = tid >> 2;
    const int skc = (tid & 3) * 8;
    const u16* ap0 = A  + (size_t)(row0 + sr)      * lda + skc;
    const u16* ap1 = A  + (size_t)(row0 + sr + 64) * lda + skc;
    const u16* bp0 = BT + (size_t)(col0 + sr)      * ldb + skc;
    const u16* bp1 = BT + (size_t)(col0 + sr + 64) * ldb + skc;
    u16* al0 = As + tid * 8;
    u16* al1 = As + tid * 8 + 64 * 32;
    u16* bl0 = Bs + tid * 8;
    u16* bl1 = Bs + tid * 8 + 64 * 32;

    for (int kt = 0; kt < K; kt += 32) {
        gload_lds16(ap0 + kt, al0);
        gload_lds16(ap1 + kt, al1);
        gload_lds16(bp0 + kt, bl0);
        gload_lds16(bp1 + kt, bl1);
        __syncthreads();

        short8 af[4], bf[4];
#pragma unroll
        for (int mi = 0; mi < 4; ++mi)
            af[mi] = *(const short8*)(As + (wr + mi * 16 + l16) * 32 + quad * 8);
#pragma unroll
        for (int ni = 0; ni < 4; ++ni)
            bf[ni] = *(const short8*)(Bs + (wc + ni * 16 + l16) * 32 + quad * 8);
#pragma unroll
        for (int mi = 0; mi < 4; ++mi)
#pragma unroll
            for (int ni = 0; ni < 4; ++ni)
                acc[mi][ni] = __builtin_amdgcn_mfma_f32_16x16x32_bf16(
                    af[mi], bf[ni], acc[mi][ni], 0, 0, 0);
        __syncthreads();
    }

#pragma unroll
    for (int mi = 0; mi < 4; ++mi) {
#pragma unroll
        for (int ni = 0; ni < 4; ++ni) {
            const int col_g = col0 + wc + ni * 16 + l16;
            if (col_g < Nreal) {
#pragma unroll
                for (int r = 0; r < 4; ++r) {
                    const int row_g = row0 + wr + mi * 16 + quad * 4 + r;
                    if (BF16_OUT)
                        ((u16*)C)[(size_t)row_g * ldc + col_g] = f2bf(acc[mi][ni][r]);
                    else
                        ((float*)C)[(size_t)row_g * ldc + col_g] = acc[mi][ni][r];
                }
            }
        }
    }
}

// ---------------- RMSNorm: bf16 strided in -> bf16 compact out (vectorized) ----------------
__global__ __launch_bounds__(256) void rmsnorm_bf_k(const u16* __restrict__ x,
                                                    const float* __restrict__ w,
                                                    u16* __restrict__ y,
                                                    int width, int stride, int off)
{
    const int row = blockIdx.x;
    const u16* xr = x + (size_t)row * stride + off;
    const int nch = width >> 3;
    float ss = 0.f;
    for (int i = threadIdx.x; i < nch; i += 256) {
        short8 v = *(const short8*)(xr + i * 8);
#pragma unroll
        for (int j = 0; j < 8; ++j) { const float f = bf2f((u16)v[j]); ss += f * f; }
    }
    __shared__ float red[256];
    red[threadIdx.x] = ss;
    __syncthreads();
    for (int s2 = 128; s2 > 0; s2 >>= 1) {
        if (threadIdx.x < s2) red[threadIdx.x] += red[threadIdx.x + s2];
        __syncthreads();
    }
    const float scale = rsqrtf(red[0] / (float)width + 1e-6f);
    u16* yr = y + (size_t)row * width;
    for (int i = threadIdx.x; i < nch; i += 256) {
        short8 v = *(const short8*)(xr + i * 8);
        const float4 w0 = *(const float4*)(w + i * 8);
        const float4 w1 = *(const float4*)(w + i * 8 + 4);
        short8 o;
        o[0] = (short)f2bf(bf2f((u16)v[0]) * scale * w0.x);
        o[1] = (short)f2bf(bf2f((u16)v[1]) * scale * w0.y);
        o[2] = (short)f2bf(bf2f((u16)v[2]) * scale * w0.z);
        o[3] = (short)f2bf(bf2f((u16)v[3]) * scale * w0.w);
        o[4] = (short)f2bf(bf2f((u16)v[4]) * scale * w1.x);
        o[5] = (short)f2bf(bf2f((u16)v[5]) * scale * w1.y);
        o[6] = (short)f2bf(bf2f((u16)v[6]) * scale * w1.z);
        o[7] = (short)f2bf(bf2f((u16)v[7]) * scale * w1.w);
        *(short8*)(yr + i * 8) = o;
    }
}

// ---------------- RoPE on q (bf16 in) + llama_4 scaling -> bf16 out (vectorized) ----------------
__global__ __launch_bounds__(256) void rope_scale_q_bf_k(const u16* __restrict__ q, const int* __restrict__ positions,
                                  const float* __restrict__ scaling,
                                  const float* __restrict__ cs_cache, u16* __restrict__ qb)
{
    const int t = blockIdx.x;
    const int pos = positions[t];
    const float* cs = cs_cache + (size_t)pos * DR;
    const float s = scaling[t];
    __shared__ float c_sh[32], s_sh[32];
    if (threadIdx.x < 32) {
        c_sh[threadIdx.x] = cs[threadIdx.x];
        s_sh[threadIdx.x] = cs[32 + threadIdx.x];
    }
    __syncthreads();
    const u16* qt = q + (size_t)t * NH * DQK;
    u16* qo = qb + (size_t)t * NH * DQK;
    for (int cc = threadIdx.x; cc < NH * 20; cc += 256) {
        const int hh = cc / 20, c = cc % 20;
        const u16* qr = qt + hh * DQK;
        u16* qw = qo + hh * DQK;
        if (c < 16) {
            short8 v = *(const short8*)(qr + c * 8);
            short8 o;
#pragma unroll
            for (int j = 0; j < 8; ++j) o[j] = (short)f2bf(bf2f((u16)v[j]) * s);
            *(short8*)(qw + c * 8) = o;
        } else {
            const int d0 = (c - 16) * 8;
            short8 x1 = *(const short8*)(qr + 128 + d0);
            short8 x2 = *(const short8*)(qr + 160 + d0);
            short8 o1, o2;
#pragma unroll
            for (int j = 0; j < 8; ++j) {
                const float a = bf2f((u16)x1[j]), b = bf2f((u16)x2[j]);
                const float cv = c_sh[d0 + j], sv = s_sh[d0 + j];
                o1[j] = (short)f2bf((a * cv - b * sv) * s);
                o2[j] = (short)f2bf((b * cv + a * sv) * s);
            }
            *(short8*)(qw + 128 + d0) = o1;
            *(short8*)(qw + 160 + d0) = o2;
        }
    }
}

// ---------------- RoPE on k_pe (pre-norm merged-latent tail, bf16) -> bf16 ----------------
__global__ void rope_k_bf_k(const u16* __restrict__ qa_lat, u16* __restrict__ kpe,
                            const int* __restrict__ positions,
                            const float* __restrict__ cs_cache)
{
    const int t = blockIdx.x;
    const int d = threadIdx.x;
    if (d >= 32) return;
    const int pos = positions[t];
    const float* cs = cs_cache + (size_t)pos * DR;
    const float c = cs[d], sn = cs[32 + d];
    const u16* lr = qa_lat + (size_t)t * MERGED_N + QRANK + KVRANK;
    const float x1 = bf2f(lr[d]), x2 = bf2f(lr[32 + d]);
    kpe[(size_t)t * DR + d]      = f2bf(x1 * c - x2 * sn);
    kpe[(size_t)t * DR + 32 + d] = f2bf(x2 * c + x1 * sn);
}

// ---------------- transpose V: kv_bf (T,NH,256)[...,128:] -> vt (NH,DV,T) ----------------
__global__ __launch_bounds__(256) void transpose_v_k(const u16* __restrict__ kvb,
                                                     u16* __restrict__ vt)
{
    __shared__ u16 tile[64][72];
    const int t0 = blockIdx.x * 64, d0 = blockIdx.y * 64, h = blockIdx.z;
    const int tid = threadIdx.x;
    for (int cc = tid; cc < 64 * 8; cc += 256) {
        const int row = cc >> 3, c = (cc & 7) * 8;   // row=t, c=dv
        *(short8*)&tile[row][c] =
            *(const short8*)(kvb + ((size_t)(t0 + row) * NH + h) * (DN + DV) + DN + d0 + c);
    }
    __syncthreads();
    for (int cc = tid; cc < 64 * 8; cc += 256) {
        const int drow = cc >> 3, c = (cc & 7) * 8;  // drow=dv, c=t
        short8 s;
#pragma unroll
        for (int j = 0; j < 8; ++j) s[j] = tile[c + j][drow];
        *(short8*)(vt + ((size_t)h * DV + d0 + drow) * T_TOK + t0 + c) = s;
    }
}

// ---------------- bf16 MFMA flash attention v9: R5 core + block-level split-K (S=2) ----------------
// Each (h, qblk) band -> 2 blocks: s=0 tiles [0, qblk+1), s=1 tiles [qblk+1, 2(qblk+1)).
// Grid 768 = 8 chunks x 96 (2 heads x 24 qblk x 2 splits), heavy-first; 64 resident/XCD,
// 32 queued -> dynamic backfill. Each split writes raw partials (m, l, O-f32); a combine
// kernel merges. Pipeline per tile identical to R5 (counted waits, raw barriers, setprio).
#define ATT_BM 128
#define ATT_BN 64
#define KS_STRIDE 200            // u16 per row: 192 data + 8 pad
#define KS_BUF (64 * KS_STRIDE)  // u16 per buffer
__global__ __launch_bounds__(512) void attn_mfma_k(
    const u16* __restrict__ qb, const u16* __restrict__ kvb,
    const u16* __restrict__ kpeb, const u16* __restrict__ vt,
    float* __restrict__ o0, float* __restrict__ o1,
    float* __restrict__ ml0, float* __restrict__ ml1)
{
    __shared__ u16 Ks[2 * KS_BUF];    // 51.2 KB double-buffered K tile (incl. kpe)
    __shared__ u16 Ps[8][16][72];     // per-wave P bounce, +8 pad

    const int tid  = threadIdx.x;
    const int wave = tid >> 6;
    const int lane = tid & 63;
    const int quad = lane >> 4;
    const int l16  = lane & 15;

    // XCD-chunked mapping: bid%8 -> XCD, 96/chunk = 2 heads x 24 qblk x 2 splits.
    const int bid   = (int)blockIdx.x;
    const int chunk = bid & 7;
    const int local = bid >> 3;                 // 0..95
    const int qblk  = 23 - (local >> 2);        // heavy bands first
    const int h     = chunk * 2 + ((local >> 1) & 1);
    const int sK    = local & 1;                // key-range split
    const int q0    = qblk * ATT_BM;
    const int wrow0 = q0 + wave * 16;
    const int qrow  = wrow0 + l16;

    short8 qf[6];
    {
        const u16* qp = qb + ((size_t)qrow * NH + h) * DQK + quad * 8;
#pragma unroll
        for (int c = 0; c < 6; ++c)
            qf[c] = *(const short8*)(qp + c * 32);
    }

    // staging descriptors: 64 rows x 24 chunks of 16B = 1536 -> 3 per thread
    const u16* gp0; const u16* gp1; const u16* gp2;
    size_t gs0, gs1, gs2;
    int lo0, lo1, lo2;
    {
        const int cc0 = tid,       r0 = cc0 / 24, c0 = cc0 % 24;
        const int cc1 = tid + 512, r1 = cc1 / 24, c1 = cc1 % 24;
        const int cc2 = tid + 1024, r2 = cc2 / 24, c2 = cc2 % 24;
        gp0 = (c0 < 16) ? kvb + ((size_t)r0 * NH + h) * (DN + DV) + c0 * 8
                        : kpeb + (size_t)r0 * DR + (c0 - 16) * 8;
        gs0 = (c0 < 16) ? (size_t)ATT_BN * NH * (DN + DV) : (size_t)ATT_BN * DR;
        lo0 = r0 * KS_STRIDE + c0 * 8;
        gp1 = (c1 < 16) ? kvb + ((size_t)r1 * NH + h) * (DN + DV) + c1 * 8
                        : kpeb + (size_t)r1 * DR + (c1 - 16) * 8;
        gs1 = (c1 < 16) ? (size_t)ATT_BN * NH * (DN + DV) : (size_t)ATT_BN * DR;
        lo1 = r1 * KS_STRIDE + c1 * 8;
        gp2 = (c2 < 16) ? kvb + ((size_t)r2 * NH + h) * (DN + DV) + c2 * 8
                        : kpeb + (size_t)r2 * DR + (c2 - 16) * 8;
        gs2 = (c2 < 16) ? (size_t)ATT_BN * NH * (DN + DV) : (size_t)ATT_BN * DR;
        lo2 = r2 * KS_STRIDE + c2 * 8;
    }

    f32x4 oacc[8];
#pragma unroll
    for (int t = 0; t < 8; ++t) oacc[t] = (f32x4){0.f, 0.f, 0.f, 0.f};
    float m_old[4], l_run[4];
#pragma unroll
    for (int r = 0; r < 4; ++r) { m_old[r] = -1e30f; l_run[r] = 0.f; }

    const u16* vbase = vt + ((size_t)h * DV + l16) * T_TOK + quad * 8;
    const int halfn = qblk + 1;
    const int ktBeg = sK * halfn;
    const int ktEnd = ktBeg + halfn;            // split covers halfn tiles

    // prologue: tile ktBeg -> regs -> buf0; tile ktBeg+1 loads in flight
    short8 s0 = *(const short8*)(gp0 + (size_t)ktBeg * gs0);
    short8 s1 = *(const short8*)(gp1 + (size_t)ktBeg * gs1);
    short8 s2 = *(const short8*)(gp2 + (size_t)ktBeg * gs2);
    asm volatile("s_waitcnt vmcnt(0)" ::: "memory");
    *(short8*)(Ks + lo0) = s0;
    *(short8*)(Ks + lo1) = s1;
    *(short8*)(Ks + lo2) = s2;
    s0 = *(const short8*)(gp0 + (size_t)(ktBeg + 1) * gs0);
    s1 = *(const short8*)(gp1 + (size_t)(ktBeg + 1) * gs1);
    s2 = *(const short8*)(gp2 + (size_t)(ktBeg + 1) * gs2);
    asm volatile("s_waitcnt vmcnt(0) lgkmcnt(0)" ::: "memory");
    __builtin_amdgcn_s_barrier();
    __builtin_amdgcn_sched_barrier(0);

    int cur = 0;
    for (int kt = ktBeg; kt < ktEnd; ++kt) {
        // stage tile kt+1 from regs into the other buffer (overlaps compute below)
        if (kt + 1 < ktEnd) {
            u16* wp = Ks + (cur ^ 1) * KS_BUF;
            *(short8*)(wp + lo0) = s0;
            *(short8*)(wp + lo1) = s1;
            *(short8*)(wp + lo2) = s2;
        }
        // issue tile kt+2 loads -> regs (complete by this iter's end-wait)
        if (kt + 2 < ktEnd) {
            const size_t o = (size_t)(kt + 2);
            s0 = *(const short8*)(gp0 + o * gs0);
            s1 = *(const short8*)(gp1 + o * gs1);
            s2 = *(const short8*)(gp2 + o * gs2);
        }

        const int k0 = kt * ATT_BN;
        if (k0 <= wrow0 + 15) {                 // wave has >=1 unmasked row
            const u16* kb = Ks + cur * KS_BUF;
            f32x4 sacc[4];
#pragma unroll
            for (int t = 0; t < 4; ++t) sacc[t] = (f32x4){0.f, 0.f, 0.f, 0.f};
            __builtin_amdgcn_s_setprio(1);
#pragma unroll
            for (int t = 0; t < 4; ++t) {
                const u16* kp = kb + (t * 16 + l16) * KS_STRIDE + quad * 8;
#pragma unroll
                for (int c = 0; c < 6; ++c) {
                    short8 bfrag = *(const short8*)(kp + c * 32);
                    sacc[t] = __builtin_amdgcn_mfma_f32_16x16x32_bf16(qf[c], bfrag, sacc[t], 0, 0, 0);
                }
            }
            __builtin_amdgcn_s_setprio(0);
            // prefetch V ch0 under softmax (independent of P)
            short8 vv[8];
#pragma unroll
            for (int t = 0; t < 8; ++t)
                vv[t] = *(const short8*)(vbase + (size_t)t * 16 * T_TOK + k0);

            const float sc = 0.07216878364870322f;   // 1/sqrt(192)
            const int rbase = wrow0 + quad * 4;
            if (k0 + ATT_BN - 1 > wrow0) {
                // diagonal-ish: causal mask
#pragma unroll
                for (int t = 0; t < 4; ++t) {
                    const int colg = k0 + t * 16 + l16;
#pragma unroll
                    for (int r = 0; r < 4; ++r) {
                        const float s = sacc[t][r] * sc;
                        sacc[t][r] = (rbase + r >= colg) ? s : -1e30f;
                    }
                }
            } else {
#pragma unroll
                for (int t = 0; t < 4; ++t)
#pragma unroll
                    for (int r = 0; r < 4; ++r) sacc[t][r] *= sc;
            }
            float alpha[4];
#pragma unroll
            for (int r = 0; r < 4; ++r) {
                float mx = fmaxf(fmaxf(sacc[0][r], sacc[1][r]), fmaxf(sacc[2][r], sacc[3][r]));
                mx = fmaxf(mx, __shfl_xor(mx, 1));
                mx = fmaxf(mx, __shfl_xor(mx, 2));
                mx = fmaxf(mx, __shfl_xor(mx, 4));
                mx = fmaxf(mx, __shfl_xor(mx, 8));
                const float mnew = fmaxf(m_old[r], mx);
                alpha[r] = __expf(m_old[r] - mnew);
                float sum = 0.f;
#pragma unroll
                for (int t = 0; t < 4; ++t) {
                    const float p = __expf(sacc[t][r] - mnew);
                    sacc[t][r] = p;
                    sum += p;
                }
                sum += __shfl_xor(sum, 1);
                sum += __shfl_xor(sum, 2);
                sum += __shfl_xor(sum, 4);
                sum += __shfl_xor(sum, 8);
                l_run[r] = l_run[r] * alpha[r] + sum;
                m_old[r] = mnew;
            }
            // P (C-layout) -> per-wave LDS as bf16 (A-layout source for PV)
#pragma unroll
            for (int t = 0; t < 4; ++t)
#pragma unroll
                for (int r = 0; r < 4; ++r)
                    Ps[wave][quad * 4 + r][t * 16 + l16] = f2bf(sacc[t][r]);
            // issue V ch1 now: lands under Ps readback + PV ch0 MFMAs
            short8 ww[8];
#pragma unroll
            for (int t = 0; t < 8; ++t)
                ww[t] = *(const short8*)(vbase + (size_t)t * 16 * T_TOK + k0 + 32);
#pragma unroll
            for (int t = 0; t < 8; ++t)
#pragma unroll
                for (int r = 0; r < 4; ++r)
                    oacc[t][r] *= alpha[r];
            // same-wave LDS write->read: compiler-inserted lgkmcnt, no barrier needed
            short8 pfrag0 = *(const short8*)&Ps[wave][l16][quad * 8];
            short8 pfrag1 = *(const short8*)&Ps[wave][l16][32 + quad * 8];
            __builtin_amdgcn_s_setprio(1);
#pragma unroll
            for (int t = 0; t < 8; ++t)
                oacc[t] = __builtin_amdgcn_mfma_f32_16x16x32_bf16(pfrag0, vv[t], oacc[t], 0, 0, 0);
#pragma unroll
            for (int t = 0; t < 8; ++t)
                oacc[t] = __builtin_amdgcn_mfma_f32_16x16x32_bf16(pfrag1, ww[t], oacc[t], 0, 0, 0);
            __builtin_amdgcn_s_setprio(0);
        }

        // end-of-tile sync: loads for kt+2 had the whole compute to land
        asm volatile("s_waitcnt vmcnt(0) lgkmcnt(0)" ::: "memory");
        __builtin_amdgcn_s_barrier();
        __builtin_amdgcn_sched_barrier(0);
        cur ^= 1;
    }

    // ---- write raw partials (m, l, O-f32); combine kernel merges the two splits ----
    float* opart = sK ? o1 : o0;
    float* mlp   = sK ? ml1 : ml0;
#pragma unroll
    for (int r = 0; r < 4; ++r) {
        const int row_g = wrow0 + quad * 4 + r;
        float* op = opart + ((size_t)row_g * NH + h) * DV;
#pragma unroll
        for (int t = 0; t < 8; ++t)
            op[t * 16 + l16] = oacc[t][r];
        if (l16 == 0) {
            float* mp = mlp + ((size_t)row_g * NH + h) * 2;
            mp[0] = m_old[r];
            mp[1] = l_run[r];
        }
    }
}

// ---------------- combine the two split-K partials -> bf16 attnb ----------------
__global__ __launch_bounds__(256) void attn_combine_k(
    const float* __restrict__ o0, const float* __restrict__ o1,
    const float* __restrict__ ml0, const float* __restrict__ ml1,
    u16* __restrict__ attnb)
{
    const int row = blockIdx.x * 8 + (threadIdx.x >> 5);   // row in [0, T*NH)
    const int c   = (threadIdx.x & 31) * 4;
    const float2 a = *(const float2*)(ml0 + (size_t)row * 2);
    const float2 b = *(const float2*)(ml1 + (size_t)row * 2);
    const float m  = fmaxf(a.x, b.x);
    const float wA = __expf(a.x - m), wB = __expf(b.x - m);
    const float linv = 1.f / (a.y * wA + b.y * wB);
    const float4 va = *(const float4*)(o0 + (size_t)row * DV + c);
    const float4 vb = *(const float4*)(o1 + (size_t)row * DV + c);
    ushort4 o;
    o.x = f2bf((va.x * wA + vb.x * wB) * linv);
    o.y = f2bf((va.y * wA + vb.y * wB) * linv);
    o.z = f2bf((va.z * wA + vb.z * wB) * linv);
    o.w = f2bf((va.w * wA + vb.w * wB) * linv);
    *(ushort4*)(attnb + (size_t)row * DV + c) = o;
}

extern "C" void kernel_launch(void* const* d_in, const int* in_sizes, int n_in,
                              void* d_out, int out_size, void* d_ws, size_t ws_size,
                              hipStream_t stream)
{
    const int*   positions = (const int*)d_in[0];
    const float* hidden    = (const float*)d_in[1];
    const float* scaling   = (const float*)d_in[2];
    const float* w_q_a     = (const float*)d_in[3];
    const float* q_a_ln_w  = (const float*)d_in[4];
    const float* w_q_b     = (const float*)d_in[5];
    const float* w_kv_a    = (const float*)d_in[6];
    const float* kv_a_ln_w = (const float*)d_in[7];
    const float* w_kv_b    = (const float*)d_in[8];
    const float* w_o       = (const float*)d_in[9];
    const float* cs_cache  = (const float*)d_in[10];
    float* out = (float*)d_out;

    char* p = (char*)d_ws;
    auto alloc = [&](size_t bytes) { char* r = p; p += (bytes + 255) & ~(size_t)255; return r; };

    // region H: hidden_bf (31.5MB) -> qraw_bf (18.9MB) -> split-0 O partial (25.2MB f32)
    char* regH      = alloc((size_t)T_TOK * HID_D * 2);
    u16*  hidden_bf = (u16*)regH;
    u16*  qraw_bf   = (u16*)regH;
    float* attn_o0  = (float*)regH;
    // region Q: qa_lat (13.4MB) + q_a_norm (9.4MB); later reused as qb (18.9MB)
    char* regQ      = alloc((size_t)T_TOK * MERGED_N * 2 + (size_t)T_TOK * QRANK * 2);
    u16*  qa_lat    = (u16*)regQ;
    u16*  q_a_norm  = (u16*)(regQ + (size_t)T_TOK * MERGED_N * 2);
    u16*  qb        = (u16*)regQ;
    u16* kv_a_norm = (u16*)alloc((size_t)T_TOK * KVRANK * 2);
    u16* kpe_bf    = (u16*)alloc((size_t)T_TOK * DR * 2);
    u16* kv_bf     = (u16*)alloc((size_t)T_TOK * NH * (DN + DV) * 2);
    u16* vt        = (u16*)alloc((size_t)NH * DV * T_TOK * 2);
    u16* attnb     = (u16*)alloc((size_t)T_TOK * NH * DV * 2);
    u16* wqakva_bt = (u16*)alloc((size_t)MERGED_N * HID_D * 2);
    u16* wqb_bt    = (u16*)alloc((size_t)(NH * DQK) * QRANK * 2);
    u16* wkvb_bt   = (u16*)alloc((size_t)(NH * (DN + DV)) * KVRANK * 2);
    u16* wo_bt     = (u16*)alloc((size_t)HID_D * (NH * DV) * 2);
    float* attn_o1 = (float*)alloc((size_t)T_TOK * NH * DV * 4);
    float* attn_ml0 = (float*)alloc((size_t)T_TOK * NH * 2 * 4);
    float* attn_ml1 = (float*)alloc((size_t)T_TOK * NH * 2 * 4);

    const dim3 blk(256);

    convert_bf_k<<<dim3((T_TOK * HID_D / 4 + 255) / 256), blk, 0, stream>>>(
        hidden, hidden_bf, T_TOK * HID_D / 4);
    // merged weight transpose: rows [0,1536) = w_q_a^T, rows [1536,2176) = w_kv_a^T (zero-padded)
    transpose_conv_k<<<dim3(QRANK / 32, HID_D / 32), blk, 0, stream>>>(
        w_q_a, wqakva_bt, HID_D, QRANK);
    transpose_conv_k<<<dim3(640 / 32, HID_D / 32), blk, 0, stream>>>(
        w_kv_a, wqakva_bt + (size_t)QRANK * HID_D, HID_D, KVRANK + DR);
    transpose_conv_k<<<dim3(NH * DQK / 32, QRANK / 32), blk, 0, stream>>>(w_q_b, wqb_bt, QRANK, NH * DQK);
    transpose_conv_k<<<dim3(NH * (DN + DV) / 32, KVRANK / 32), blk, 0, stream>>>(w_kv_b, wkvb_bt, KVRANK, NH * (DN + DV));
    transpose_conv_k<<<dim3(HID_D / 32, NH * DV / 32), blk, 0, stream>>>(w_o, wo_bt, NH * DV, HID_D);

    // merged G1+G2: qa_lat = hidden @ [w_q_a | w_kv_a]  (bf16 out, Nreal=2112)
    bgemm_bt_k<true><<<dim3(MERGED_N / 128, T_TOK / 128), blk, 0, stream>>>(
        hidden_bf, wqakva_bt, qa_lat, QRANK + KVRANK + DR, HID_D, HID_D, HID_D, MERGED_N);
    // k_pe rope from pre-norm latent tail (cols 2048..2111 of qa_lat)
    rope_k_bf_k<<<dim3(T_TOK), dim3(64), 0, stream>>>(qa_lat, kpe_bf, positions, cs_cache);
    // rmsnorms -> compact bf16
    rmsnorm_bf_k<<<dim3(T_TOK), blk, 0, stream>>>(qa_lat, q_a_ln_w, q_a_norm, QRANK, MERGED_N, 0);
    rmsnorm_bf_k<<<dim3(T_TOK), blk, 0, stream>>>(qa_lat, kv_a_ln_w, kv_a_norm, KVRANK, MERGED_N, QRANK);
    // G3: qraw = q_a_norm @ w_q_b  (bf16 out, into region H)
    bgemm_bt_k<true><<<dim3(NH * DQK / 128, T_TOK / 128), blk, 0, stream>>>(
        q_a_norm, wqb_bt, qraw_bf, NH * DQK, QRANK, QRANK, QRANK, NH * DQK);
    // rope + scaling on q -> qb (region Q; qa_lat/q_a_norm dead)
    rope_scale_q_bf_k<<<dim3(T_TOK), blk, 0, stream>>>(qraw_bf, positions, scaling, cs_cache, qb);
    // G4: kv = kv_a_norm @ w_kv_b  (bf16 out)
    bgemm_bt_k<true><<<dim3(NH * (DN + DV) / 128, T_TOK / 128), blk, 0, stream>>>(
        kv_a_norm, wkvb_bt, kv_bf, NH * (DN + DV), KVRANK, KVRANK, KVRANK, NH * (DN + DV));
    // global V transpose: vt[h][dv][t]
    transpose_v_k<<<dim3(T_TOK / 64, DV / 64, NH), blk, 0, stream>>>(kv_bf, vt);
    // flash attention v9: split-K(2) partials (region H reused for split-0 O)
    attn_mfma_k<<<dim3(768), dim3(512), 0, stream>>>(qb, kv_bf, kpe_bf, vt,
                                                     attn_o0, attn_o1, attn_ml0, attn_ml1);
    // combine partials -> bf16 attnb
    attn_combine_k<<<dim3(T_TOK * NH / 8), blk, 0, stream>>>(
        attn_o0, attn_o1, attn_ml0, attn_ml1, attnb);
    // G5: out = attn @ w_o  (fp32 out)
    bgemm_bt_k<false><<<dim3(HID_D / 128, T_TOK / 128), blk, 0, stream>>>(
        attnb, wo_bt, out, HID_D, NH * DV, NH * DV, NH * DV, HID_D);
}